// Round 7
// baseline (202.550 us; speedup 1.0000x reference)
//
#include <hip/hip_runtime.h>

typedef float f32x4 __attribute__((ext_vector_type(4)));
typedef short s16x8 __attribute__((ext_vector_type(8)));

#define NROWS 8192
#define DIM   512
#define ALPHA 40.0f
#define BASEV 0.5f
#define BIGF  1e9f
#define NPANEL 64          // 64 panels of 128 rows
#define NPAIRS 2080        // 64*65/2 triangular pairs
#define NSLOT  64          // partial slots per row

// workspace offsets (bytes)
#define OFF_HI   0ull
#define OFF_LO   (OFF_HI + (unsigned long long)NROWS*DIM*2)     // 8 MB
#define OFF_MAXP (OFF_LO + (unsigned long long)NROWS*DIM*2)     // 16 MB
#define OFF_SBLK (OFF_MAXP + (unsigned long long)NROWS*4)
#define OFF_PMIN (OFF_SBLK + 1024ull*64*4)
#define OFF_PCNT (OFF_PMIN + (unsigned long long)NSLOT*NROWS*4)
#define OFF_PSUM (OFF_PCNT + (unsigned long long)NSLOT*NROWS*4)
#define OFF_PEXP (OFF_PSUM + (unsigned long long)NSLOT*NROWS*4)
#define OFF_RLOSS (OFF_PEXP + (unsigned long long)NSLOT*NROWS*4)
#define OFF_RTRIP (OFF_RLOSS + (unsigned long long)NROWS*4)

__device__ inline unsigned short bf16rne(float x) {
    unsigned u = __float_as_uint(x);
    unsigned r = (u + 0x7FFFu + ((u >> 16) & 1u)) >> 16;
    return (unsigned short)r;
}

// ---------------- kernel 0: fp32 -> bf16 hi/lo, chunk-transposed [k/8][row][8]
__global__ __launch_bounds__(256) void k_prep(const float* __restrict__ emb,
                                              uint4* __restrict__ hi, uint4* __restrict__ lo) {
    int tid = blockIdx.x * 256 + threadIdx.x;
    int row = tid & (NROWS - 1);
    int chunk = tid >> 13;
    const float4* s4 = (const float4*)(emb + row * DIM + chunk * 8);
    float4 x0 = s4[0], x1 = s4[1];
    float xs[8] = {x0.x, x0.y, x0.z, x0.w, x1.x, x1.y, x1.z, x1.w};
    unsigned hw[4], lw[4];
#pragma unroll
    for (int p = 0; p < 4; ++p) {
        unsigned short h0 = bf16rne(xs[2 * p]);
        unsigned short h1 = bf16rne(xs[2 * p + 1]);
        float hf0 = __uint_as_float(((unsigned)h0) << 16);
        float hf1 = __uint_as_float(((unsigned)h1) << 16);
        unsigned short l0 = bf16rne(xs[2 * p] - hf0);
        unsigned short l1 = bf16rne(xs[2 * p + 1] - hf1);
        hw[p] = (unsigned)h0 | ((unsigned)h1 << 16);
        lw[p] = (unsigned)l0 | ((unsigned)l1 << 16);
    }
    uint4 H = {hw[0], hw[1], hw[2], hw[3]};
    uint4 L = {lw[0], lw[1], lw[2], lw[3]};
    hi[chunk * NROWS + row] = H;
    lo[chunk * NROWS + row] = L;
}

// ---------------- kernel 1: per-class 8x8 fp32 Gram -> simblk, max_pos
__global__ __launch_bounds__(64) void k_gram(const float* __restrict__ emb,
                                             float* __restrict__ simblk,
                                             float* __restrict__ maxpos) {
    __shared__ float A[8 * 516];
    int cls = blockIdx.x, t = threadIdx.x;
    const float* base = emb + (size_t)cls * 8 * DIM;
    for (int it = 0; it < 64; ++it) {
        int idx = t + 64 * it;
        int r = idx >> 9, k = idx & 511;
        A[r * 516 + k] = base[idx];
    }
    __syncthreads();
    int i = t >> 3, j = t & 7;
    const float* ai = A + i * 516;
    const float* aj = A + j * 516;
    float s = 0.f;
    for (int k = 0; k < 512; ++k) s += ai[k] * aj[k];
    simblk[cls * 64 + t] = s;
    float m = (i == j) ? -BIGF : s;
#pragma unroll
    for (int off = 1; off < 8; off <<= 1) m = fmaxf(m, __shfl_xor(m, off, 64));
    if (j == 0) maxpos[cls * 8 + i] = m;
}

// ---------------- kernel 2: symmetric triangular pair-block GEMM, reg-direct,
// high-TLP variant: 512 threads / 8 waves per block, wave-tile 64x32 -> acc=32
// regs; total regs <=128 (unified VGPR+AGPR file) -> 4 waves/SIMD resident.
__global__ __launch_bounds__(512, 4) void k_main(const unsigned short* __restrict__ ehi,
                                                 const unsigned short* __restrict__ elo,
                                                 const float* __restrict__ maxpos,
                                                 float* __restrict__ pmin,
                                                 unsigned* __restrict__ pcnt,
                                                 float* __restrict__ psum,
                                                 float* __restrict__ pexp) {
    __shared__ float sMaxA[128], sMaxB[128];
    __shared__ float rMin[4][128];             // [wcq][row]
    __shared__ unsigned rCnt[4][128];
    __shared__ float rSum[4][128], rExp[4][128];
    __shared__ float cMin[2][128];             // [wr][col]
    __shared__ unsigned cCnt[2][128];
    __shared__ float cSum[2][128], cExp[2][128];

    int t = threadIdx.x;
    int lane = t & 63;
    int w = t >> 6;            // wave 0..7
    int wr = w >> 2;           // row half 0..1   (64 rows each)
    int wcq = w & 3;           // col quarter 0..3 (32 cols each)

    // XCD-chunked bijective swizzle (2080 = 8*260)
    int bid = blockIdx.x;
    int wg = (bid & 7) * 260 + (bid >> 3);
    // triangular unranking: J-major, I = 0..J  (consecutive wg share J-panel -> L2)
    int J = (int)((sqrtf(8.0f * (float)wg + 1.0f) - 1.0f) * 0.5f);
    while ((J + 1) * (J + 2) / 2 <= wg) ++J;
    while (J * (J + 1) / 2 > wg) --J;
    int I = wg - J * (J + 1) / 2;
    int r0 = I * 128, c0 = J * 128;
    bool diag = (I == J);

    if (t < 128) sMaxA[t] = maxpos[r0 + t];
    else if (t < 256) sMaxB[t - 128] = maxpos[c0 + (t - 128)];
    // visibility guaranteed by the pre-epilogue __syncthreads()

    int rl = (lane >> 4) * 4;     // C/D layout row sub-offset
    int ri = lane & 15;
    int cg = lane >> 4;           // k-chunk group 0..3

    // per-lane fragment row indices (s16x8 units; arrays are [chunk][row][8])
    int arow = r0 + wr * 64 + ri;
    int brow = c0 + wcq * 32 + ri;
    const s16x8* Ehi = (const s16x8*)ehi;
    const s16x8* Elo = (const s16x8*)elo;

    f32x4 acc[4][2];
#pragma unroll
    for (int m = 0; m < 4; ++m)
#pragma unroll
        for (int n = 0; n < 2; ++n) acc[m][n] = (f32x4){0.f, 0.f, 0.f, 0.f};

#pragma unroll 2
    for (int kt = 0; kt < 16; ++kt) {
        size_t kb = (size_t)(kt * 4 + cg) * NROWS;   // K=32 slice: chunks kt*4+cg
        const s16x8* pAh = Ehi + kb + arow;
        const s16x8* pAl = Elo + kb + arow;
        const s16x8* pBh = Ehi + kb + brow;
        const s16x8* pBl = Elo + kb + brow;
        s16x8 aH[4], aL[4], bH[2], bL[2];
#pragma unroll
        for (int m = 0; m < 4; ++m) { aH[m] = pAh[m * 16]; aL[m] = pAl[m * 16]; }
#pragma unroll
        for (int n = 0; n < 2; ++n) { bH[n] = pBh[n * 16]; bL[n] = pBl[n * 16]; }
#pragma unroll
        for (int m = 0; m < 4; ++m)
#pragma unroll
            for (int n = 0; n < 2; ++n) {
                acc[m][n] = __builtin_amdgcn_mfma_f32_16x16x32_bf16(aH[m], bH[n], acc[m][n], 0, 0, 0);
                acc[m][n] = __builtin_amdgcn_mfma_f32_16x16x32_bf16(aH[m], bL[n], acc[m][n], 0, 0, 0);
                acc[m][n] = __builtin_amdgcn_mfma_f32_16x16x32_bf16(aL[m], bH[n], acc[m][n], 0, 0, 0);
            }
    }

    __syncthreads();   // sMaxA/B visible; no other cross-wave deps before here

    // -------- 2-sided epilogue over the 128x128 tile (this wave: 64x32) --------
    float mxB[2];
#pragma unroll
    for (int n = 0; n < 2; ++n) mxB[n] = sMaxB[wcq * 32 + n * 16 + ri];

    float cmn[2], csm[2], ces[2];
    int cct[2];
#pragma unroll
    for (int n = 0; n < 2; ++n) { cmn[n] = BIGF; csm[n] = 0.f; ces[n] = 0.f; cct[n] = 0; }

#pragma unroll
    for (int m = 0; m < 4; ++m) {
#pragma unroll
        for (int jj = 0; jj < 4; ++jj) {
            int lr0 = wr * 64 + m * 16 + rl + jj;
            int grow = r0 + lr0;
            int rcls = grow >> 3;
            float mxA = sMaxA[lr0];
            float mn = BIGF, sm = 0.f, es = 0.f;
            int ct = 0;
#pragma unroll
            for (int n = 0; n < 2; ++n) {
                float v = acc[m][n][jj];
                int gcol = c0 + wcq * 32 + n * 16 + ri;
                if ((gcol >> 3) != rcls) {
                    float e = __expf(ALPHA * (v - BASEV));   // shared by both gates
                    mn = fminf(mn, v);
                    if (v < mxA) { ct++; sm += v; es += e; }
                    if (!diag) {
                        cmn[n] = fminf(cmn[n], v);
                        if (v < mxB[n]) { cct[n]++; csm[n] += v; ces[n] += e; }
                    }
                }
            }
#pragma unroll
            for (int off = 1; off < 16; off <<= 1) {   // reduce 16 cols (ri groups)
                mn = fminf(mn, __shfl_xor(mn, off, 64));
                sm += __shfl_xor(sm, off, 64);
                es += __shfl_xor(es, off, 64);
                ct += __shfl_xor(ct, off, 64);
            }
            if ((lane & 15) == 0) {   // single writer per (wcq, lr0)
                rMin[wcq][lr0] = mn;
                rCnt[wcq][lr0] = (unsigned)ct;
                rSum[wcq][lr0] = sm;
                rExp[wcq][lr0] = es;
            }
        }
    }

    if (!diag) {
#pragma unroll
        for (int n = 0; n < 2; ++n) {
#pragma unroll
            for (int off = 16; off < 64; off <<= 1) {   // reduce over rl-groups (rows)
                cmn[n] = fminf(cmn[n], __shfl_xor(cmn[n], off, 64));
                csm[n] += __shfl_xor(csm[n], off, 64);
                ces[n] += __shfl_xor(ces[n], off, 64);
                cct[n] += __shfl_xor(cct[n], off, 64);
            }
        }
        if (lane < 16) {
#pragma unroll
            for (int n = 0; n < 2; ++n) {
                int lc = wcq * 32 + n * 16 + ri;
                cMin[wr][lc] = cmn[n];
                cCnt[wr][lc] = (unsigned)cct[n];
                cSum[wr][lc] = csm[n];
                cExp[wr][lc] = ces[n];
            }
        }
    }

    __syncthreads();
    if (t < 128) {
        // rows of panel I, slot J (merge the four wcq col-quarters)
        int gi = J * NROWS + r0 + t;
        pmin[gi] = fminf(fminf(rMin[0][t], rMin[1][t]), fminf(rMin[2][t], rMin[3][t]));
        pcnt[gi] = rCnt[0][t] + rCnt[1][t] + rCnt[2][t] + rCnt[3][t];
        psum[gi] = ((rSum[0][t] + rSum[1][t]) + rSum[2][t]) + rSum[3][t];
        pexp[gi] = ((rExp[0][t] + rExp[1][t]) + rExp[2][t]) + rExp[3][t];
    } else if (t < 256 && !diag) {
        // rows of panel J (= cols of tile), slot I (merge the two wr row-halves)
        int tc = t - 128;
        int gi = I * NROWS + c0 + tc;
        pmin[gi] = fminf(cMin[0][tc], cMin[1][tc]);
        pcnt[gi] = cCnt[0][tc] + cCnt[1][tc];
        psum[gi] = cSum[0][tc] + cSum[1][tc];
        pexp[gi] = cExp[0][tc] + cExp[1][tc];
    }
}

// ---------------- kernel 3a: per-row combine + loss (32 blocks)
__global__ __launch_bounds__(256) void k_fin1(const float* __restrict__ pmin,
                                              const unsigned* __restrict__ pcnt,
                                              const float* __restrict__ psum,
                                              const float* __restrict__ pexp,
                                              const float* __restrict__ simblk,
                                              float* __restrict__ rowloss,
                                              unsigned* __restrict__ rowtrip) {
    int row = blockIdx.x * 256 + threadIdx.x;
    float mn = BIGF;
    unsigned ct = 0;
    float sm = 0.f, es = 0.f;
#pragma unroll 8
    for (int c = 0; c < NSLOT; ++c) {
        int gi = c * NROWS + row;
        mn = fminf(mn, pmin[gi]);
        ct += pcnt[gi];
        sm += psum[gi];
        es += pexp[gi];
    }
    int cls = row >> 3, ir = row & 7;
    const float* sb = simblk + cls * 64 + ir * 8;
    float psumv = 0.f;
    int pcntv = 0;
#pragma unroll
    for (int j = 0; j < 8; ++j) {
        if (j == ir) continue;
        float s = sb[j];
        if (s > mn) { pcntv++; psumv += 1.f - s; }
    }
    float pl = (pcntv > 0) ? psumv / (float)pcntv : 0.f;
    float nl = (ct > 0) ? (2.0f / ALPHA) * log1pf(es) + sm / (float)ct : 0.f;
    rowloss[row] = pl + nl;
    rowtrip[row] = ct >> 1;
}

// ---------------- kernel 3b: deterministic final reduce (single block)
__global__ __launch_bounds__(256) void k_fin2(const float* __restrict__ rowloss,
                                              const unsigned* __restrict__ rowtrip,
                                              float* __restrict__ out) {
    __shared__ float lsum[256];
    __shared__ unsigned long long ltrip[256];
    int t = threadIdx.x;
    float acc = 0.f;
    unsigned long long trip = 0ull;
    for (int it = 0; it < NROWS / 256; ++it) {
        int row = t + it * 256;
        acc += rowloss[row];
        trip += (unsigned long long)rowtrip[row];
    }
    lsum[t] = acc;
    ltrip[t] = trip;
    __syncthreads();
    for (int s = 128; s > 0; s >>= 1) {
        if (t < s) { lsum[t] += lsum[t + s]; ltrip[t] += ltrip[t + s]; }
        __syncthreads();
    }
    if (t == 0) {
        out[0] = lsum[0] / (float)NROWS;
        out[1] = (float)ltrip[0];
        out[2] = 0.f;
    }
}

extern "C" void kernel_launch(void* const* d_in, const int* in_sizes, int n_in,
                              void* d_out, int out_size, void* d_ws, size_t ws_size,
                              hipStream_t stream) {
    const float* emb = (const float*)d_in[0];
    char* ws = (char*)d_ws;
    unsigned short* ehi = (unsigned short*)(ws + OFF_HI);
    unsigned short* elo = (unsigned short*)(ws + OFF_LO);
    float* maxpos = (float*)(ws + OFF_MAXP);
    float* simblk = (float*)(ws + OFF_SBLK);
    float* pmin = (float*)(ws + OFF_PMIN);
    unsigned* pcnt = (unsigned*)(ws + OFF_PCNT);
    float* psum = (float*)(ws + OFF_PSUM);
    float* pexp = (float*)(ws + OFF_PEXP);
    float* rowloss = (float*)(ws + OFF_RLOSS);
    unsigned* rowtrip = (unsigned*)(ws + OFF_RTRIP);
    float* out = (float*)d_out;

    hipLaunchKernelGGL(k_prep, dim3(64 * NROWS / 256), dim3(256), 0, stream,
                       emb, (uint4*)ehi, (uint4*)elo);
    hipLaunchKernelGGL(k_gram, dim3(1024), dim3(64), 0, stream, emb, simblk, maxpos);
    hipLaunchKernelGGL(k_main, dim3(NPAIRS), dim3(512), 0, stream,
                       ehi, elo, maxpos, pmin, pcnt, psum, pexp);
    hipLaunchKernelGGL(k_fin1, dim3(NROWS / 256), dim3(256), 0, stream,
                       pmin, pcnt, psum, pexp, simblk, rowloss, rowtrip);
    hipLaunchKernelGGL(k_fin2, dim3(1), dim3(256), 0, stream, rowloss, rowtrip, out);
}

// Round 9
// 153.179 us; speedup vs baseline: 1.3223x; 1.3223x over previous
//
#include <hip/hip_runtime.h>

typedef float f32x4 __attribute__((ext_vector_type(4)));
typedef short s16x8 __attribute__((ext_vector_type(8)));

#define NROWS 8192
#define DIM   512
#define ALPHA 40.0f
#define BASEV 0.5f
#define BIGF  1e9f
#define NPANEL 64          // 64 panels of 128 rows
#define NPAIRS 2080        // 64*65/2 triangular pairs
#define NSLOT  64          // partial slots per row

// workspace offsets (bytes)
#define OFF_HI   0ull
#define OFF_LO   (OFF_HI + (unsigned long long)NROWS*DIM*2)     // 8 MB
#define OFF_MAXP (OFF_LO + (unsigned long long)NROWS*DIM*2)     // 16 MB
#define OFF_SBLK (OFF_MAXP + (unsigned long long)NROWS*4)
#define OFF_PMIN (OFF_SBLK + 1024ull*64*4)
#define OFF_PCNT (OFF_PMIN + (unsigned long long)NSLOT*NROWS*4)
#define OFF_PSUM (OFF_PCNT + (unsigned long long)NSLOT*NROWS*4)
#define OFF_PEXP (OFF_PSUM + (unsigned long long)NSLOT*NROWS*4)
#define OFF_RLOSS (OFF_PEXP + (unsigned long long)NSLOT*NROWS*4)
#define OFF_RTRIP (OFF_RLOSS + (unsigned long long)NROWS*4)

__device__ inline unsigned short bf16rne(float x) {
    unsigned u = __float_as_uint(x);
    unsigned r = (u + 0x7FFFu + ((u >> 16) & 1u)) >> 16;
    return (unsigned short)r;
}

// ---------------- kernel 0: fp32 -> bf16 hi/lo, chunk-transposed [k/8][row][8]
__global__ __launch_bounds__(256) void k_prep(const float* __restrict__ emb,
                                              uint4* __restrict__ hi, uint4* __restrict__ lo) {
    int tid = blockIdx.x * 256 + threadIdx.x;
    int row = tid & (NROWS - 1);
    int chunk = tid >> 13;
    const float4* s4 = (const float4*)(emb + row * DIM + chunk * 8);
    float4 x0 = s4[0], x1 = s4[1];
    float xs[8] = {x0.x, x0.y, x0.z, x0.w, x1.x, x1.y, x1.z, x1.w};
    unsigned hw[4], lw[4];
#pragma unroll
    for (int p = 0; p < 4; ++p) {
        unsigned short h0 = bf16rne(xs[2 * p]);
        unsigned short h1 = bf16rne(xs[2 * p + 1]);
        float hf0 = __uint_as_float(((unsigned)h0) << 16);
        float hf1 = __uint_as_float(((unsigned)h1) << 16);
        unsigned short l0 = bf16rne(xs[2 * p] - hf0);
        unsigned short l1 = bf16rne(xs[2 * p + 1] - hf1);
        hw[p] = (unsigned)h0 | ((unsigned)h1 << 16);
        lw[p] = (unsigned)l0 | ((unsigned)l1 << 16);
    }
    uint4 H = {hw[0], hw[1], hw[2], hw[3]};
    uint4 L = {lw[0], lw[1], lw[2], lw[3]};
    hi[chunk * NROWS + row] = H;
    lo[chunk * NROWS + row] = L;
}

// ---------------- kernel 1: per-class 8x8 fp32 Gram -> simblk, max_pos
__global__ __launch_bounds__(64) void k_gram(const float* __restrict__ emb,
                                             float* __restrict__ simblk,
                                             float* __restrict__ maxpos) {
    __shared__ float A[8 * 516];
    int cls = blockIdx.x, t = threadIdx.x;
    const float* base = emb + (size_t)cls * 8 * DIM;
    for (int it = 0; it < 64; ++it) {
        int idx = t + 64 * it;
        int r = idx >> 9, k = idx & 511;
        A[r * 516 + k] = base[idx];
    }
    __syncthreads();
    int i = t >> 3, j = t & 7;
    const float* ai = A + i * 516;
    const float* aj = A + j * 516;
    float s = 0.f;
    for (int k = 0; k < 512; ++k) s += ai[k] * aj[k];
    simblk[cls * 64 + t] = s;
    float m = (i == j) ? -BIGF : s;
#pragma unroll
    for (int off = 1; off < 8; off <<= 1) m = fmaxf(m, __shfl_xor(m, off, 64));
    if (j == 0) maxpos[cls * 8 + i] = m;
}

// asm-pinned 4-load group: base + {0,256,512,768} bytes (m*16 s16x8 elements).
// "=&v" EARLY-CLOBBER is mandatory: dest tuples must not alias the 64-bit
// address pair, which is read by all four loads (round-8 crash cause).
#define LD4(d0, d1, d2, d3, base)                                          \
    asm volatile("global_load_dwordx4 %0, %4, off\n\t"                     \
                 "global_load_dwordx4 %1, %4, off offset:256\n\t"          \
                 "global_load_dwordx4 %2, %4, off offset:512\n\t"          \
                 "global_load_dwordx4 %3, %4, off offset:768"              \
                 : "=&v"(d0), "=&v"(d1), "=&v"(d2), "=&v"(d3)              \
                 : "v"(base) : "memory")

#define WAITV(n)                                                           \
    do {                                                                   \
        asm volatile("s_waitcnt vmcnt(" #n ")" ::: "memory");              \
        __builtin_amdgcn_sched_barrier(0);                                 \
    } while (0)

// ---------------- kernel 2: symmetric triangular pair-block GEMM, reg-direct,
// hand-pipelined: asm-volatile loads (compiler cannot collapse the 2-deep
// prefetch) + counted vmcnt(16) that never drains to 0 in steady state.
__global__ __launch_bounds__(256, 2) void k_main(const unsigned short* __restrict__ ehi,
                                                 const unsigned short* __restrict__ elo,
                                                 const float* __restrict__ maxpos,
                                                 float* __restrict__ pmin,
                                                 unsigned* __restrict__ pcnt,
                                                 float* __restrict__ psum,
                                                 float* __restrict__ pexp) {
    __shared__ float sMaxA[128], sMaxB[128];
    __shared__ float rMin[2][128];             // [wc][row]
    __shared__ unsigned rCnt[2][128];
    __shared__ float rSum[2][128], rExp[2][128];
    __shared__ float cMin[2][128];             // [wr][col]
    __shared__ unsigned cCnt[2][128];
    __shared__ float cSum[2][128], cExp[2][128];

    int t = threadIdx.x;
    int lane = t & 63;
    int w = t >> 6;
    int wr = w >> 1, wc = w & 1;

    // XCD-chunked bijective swizzle (2080 = 8*260)
    int bid = blockIdx.x;
    int wg = (bid & 7) * 260 + (bid >> 3);
    // triangular unranking: J-major, I = 0..J  (consecutive wg share J-panel -> L2)
    int J = (int)((sqrtf(8.0f * (float)wg + 1.0f) - 1.0f) * 0.5f);
    while ((J + 1) * (J + 2) / 2 <= wg) ++J;
    while (J * (J + 1) / 2 > wg) --J;
    int I = wg - J * (J + 1) / 2;
    int r0 = I * 128, c0 = J * 128;
    bool diag = (I == J);

    if (t < 128) sMaxA[t] = maxpos[r0 + t];
    else sMaxB[t - 128] = maxpos[c0 + (t - 128)];
    // visibility guaranteed by the pre-epilogue __syncthreads()

    int rl = (lane >> 4) * 4;     // C/D layout row sub-offset
    int ri = lane & 15;
    int cg = lane >> 4;           // k-chunk group 0..3

    // per-lane fragment base addresses (bytes); arrays are [chunk][row][8 bf16]
    int arow = r0 + wr * 64 + ri;
    int brow = c0 + wc * 64 + ri;
    const char* baseAh = (const char*)((const s16x8*)ehi + (size_t)cg * NROWS + arow);
    const char* baseAl = (const char*)((const s16x8*)elo + (size_t)cg * NROWS + arow);
    const char* baseBh = (const char*)((const s16x8*)ehi + (size_t)cg * NROWS + brow);
    const char* baseBl = (const char*)((const s16x8*)elo + (size_t)cg * NROWS + brow);
    const size_t KSTEP = (size_t)4 * NROWS * 16;   // bytes per K-step (4 chunks)

    f32x4 acc[4][4];
#pragma unroll
    for (int m = 0; m < 4; ++m)
#pragma unroll
        for (int n = 0; n < 4; ++n) acc[m][n] = (f32x4){0.f, 0.f, 0.f, 0.f};

    // two named fragment sets (rule #20: static indices only)
    s16x8 aH0[4], aL0[4], bH0[4], bL0[4];
    s16x8 aH1[4], aL1[4], bH1[4], bL1[4];

#define ISSUE0(kt)                                                          \
    do {                                                                    \
        size_t o = (size_t)(kt)*KSTEP;                                      \
        LD4(aH0[0], aH0[1], aH0[2], aH0[3], baseAh + o);                    \
        LD4(aL0[0], aL0[1], aL0[2], aL0[3], baseAl + o);                    \
        LD4(bH0[0], bH0[1], bH0[2], bH0[3], baseBh + o);                    \
        LD4(bL0[0], bL0[1], bL0[2], bL0[3], baseBl + o);                    \
    } while (0)
#define ISSUE1(kt)                                                          \
    do {                                                                    \
        size_t o = (size_t)(kt)*KSTEP;                                      \
        LD4(aH1[0], aH1[1], aH1[2], aH1[3], baseAh + o);                    \
        LD4(aL1[0], aL1[1], aL1[2], aL1[3], baseAl + o);                    \
        LD4(bH1[0], bH1[1], bH1[2], bH1[3], baseBh + o);                    \
        LD4(bL1[0], bL1[1], bL1[2], bL1[3], baseBl + o);                    \
    } while (0)
#define MFMASET(aH, aL, bH, bL)                                             \
    do {                                                                    \
        _Pragma("unroll") for (int m = 0; m < 4; ++m)                       \
            _Pragma("unroll") for (int n = 0; n < 4; ++n) {                 \
                acc[m][n] = __builtin_amdgcn_mfma_f32_16x16x32_bf16(aH[m], bH[n], acc[m][n], 0, 0, 0); \
                acc[m][n] = __builtin_amdgcn_mfma_f32_16x16x32_bf16(aH[m], bL[n], acc[m][n], 0, 0, 0); \
                acc[m][n] = __builtin_amdgcn_mfma_f32_16x16x32_bf16(aL[m], bH[n], acc[m][n], 0, 0, 0); \
            }                                                               \
    } while (0)

    ISSUE0(0);
    ISSUE1(1);
#pragma unroll
    for (int kt = 0; kt < 16; kt += 2) {
        WAITV(16);                       // set0 (kt) complete; set1 still in flight
        MFMASET(aH0, aL0, bH0, bL0);
        __builtin_amdgcn_sched_barrier(0);
        if (kt + 2 < 16) {
            ISSUE0(kt + 2);
            WAITV(16);                   // set1 (kt+1) complete; set0-new in flight
        } else {
            WAITV(0);                    // tail: drain set1
        }
        MFMASET(aH1, aL1, bH1, bL1);
        __builtin_amdgcn_sched_barrier(0);
        if (kt + 3 < 16) ISSUE1(kt + 3);
    }

    __syncthreads();   // sMaxA/B visible; no other cross-wave deps before here

    // -------- 2-sided epilogue over the 128x128 tile --------
    float mxB[4];
#pragma unroll
    for (int n = 0; n < 4; ++n) mxB[n] = sMaxB[wc * 64 + n * 16 + ri];

    float cmn[4], csm[4], ces[4];
    int cct[4];
#pragma unroll
    for (int n = 0; n < 4; ++n) { cmn[n] = BIGF; csm[n] = 0.f; ces[n] = 0.f; cct[n] = 0; }

#pragma unroll
    for (int m = 0; m < 4; ++m) {
#pragma unroll
        for (int jj = 0; jj < 4; ++jj) {
            int lr0 = wr * 64 + m * 16 + rl + jj;
            int grow = r0 + lr0;
            int rcls = grow >> 3;
            float mxA = sMaxA[lr0];
            float mn = BIGF, sm = 0.f, es = 0.f;
            int ct = 0;
#pragma unroll
            for (int n = 0; n < 4; ++n) {
                float v = acc[m][n][jj];
                int gcol = c0 + wc * 64 + n * 16 + ri;
                if ((gcol >> 3) != rcls) {
                    float e = __expf(ALPHA * (v - BASEV));   // shared by both gates
                    mn = fminf(mn, v);
                    if (v < mxA) { ct++; sm += v; es += e; }
                    if (!diag) {
                        cmn[n] = fminf(cmn[n], v);
                        if (v < mxB[n]) { cct[n]++; csm[n] += v; ces[n] += e; }
                    }
                }
            }
#pragma unroll
            for (int off = 1; off < 16; off <<= 1) {
                mn = fminf(mn, __shfl_xor(mn, off, 64));
                sm += __shfl_xor(sm, off, 64);
                es += __shfl_xor(es, off, 64);
                ct += __shfl_xor(ct, off, 64);
            }
            if ((lane & 15) == 0) {   // single writer per (wc, lr0)
                rMin[wc][lr0] = mn;
                rCnt[wc][lr0] = (unsigned)ct;
                rSum[wc][lr0] = sm;
                rExp[wc][lr0] = es;
            }
        }
    }

    if (!diag) {
#pragma unroll
        for (int n = 0; n < 4; ++n) {
#pragma unroll
            for (int off = 16; off < 64; off <<= 1) {   // reduce over rl-groups
                cmn[n] = fminf(cmn[n], __shfl_xor(cmn[n], off, 64));
                csm[n] += __shfl_xor(csm[n], off, 64);
                ces[n] += __shfl_xor(ces[n], off, 64);
                cct[n] += __shfl_xor(cct[n], off, 64);
            }
        }
        if (lane < 16) {
#pragma unroll
            for (int n = 0; n < 4; ++n) {
                int lc = wc * 64 + n * 16 + ri;
                cMin[wr][lc] = cmn[n];
                cCnt[wr][lc] = (unsigned)cct[n];
                cSum[wr][lc] = csm[n];
                cExp[wr][lc] = ces[n];
            }
        }
    }

    __syncthreads();
    if (t < 128) {
        // rows of panel I, slot J (merge the two wc col-halves)
        int gi = J * NROWS + r0 + t;
        pmin[gi] = fminf(rMin[0][t], rMin[1][t]);
        pcnt[gi] = rCnt[0][t] + rCnt[1][t];
        psum[gi] = rSum[0][t] + rSum[1][t];
        pexp[gi] = rExp[0][t] + rExp[1][t];
    } else if (!diag) {
        // rows of panel J (= cols of tile), slot I (merge the two wr row-halves)
        int tc = t - 128;
        int gi = I * NROWS + c0 + tc;
        pmin[gi] = fminf(cMin[0][tc], cMin[1][tc]);
        pcnt[gi] = cCnt[0][tc] + cCnt[1][tc];
        psum[gi] = cSum[0][tc] + cSum[1][tc];
        pexp[gi] = cExp[0][tc] + cExp[1][tc];
    }
}

// ---------------- kernel 3a: per-row combine + loss (32 blocks)
__global__ __launch_bounds__(256) void k_fin1(const float* __restrict__ pmin,
                                              const unsigned* __restrict__ pcnt,
                                              const float* __restrict__ psum,
                                              const float* __restrict__ pexp,
                                              const float* __restrict__ simblk,
                                              float* __restrict__ rowloss,
                                              unsigned* __restrict__ rowtrip) {
    int row = blockIdx.x * 256 + threadIdx.x;
    float mn = BIGF;
    unsigned ct = 0;
    float sm = 0.f, es = 0.f;
#pragma unroll 8
    for (int c = 0; c < NSLOT; ++c) {
        int gi = c * NROWS + row;
        mn = fminf(mn, pmin[gi]);
        ct += pcnt[gi];
        sm += psum[gi];
        es += pexp[gi];
    }
    int cls = row >> 3, ir = row & 7;
    const float* sb = simblk + cls * 64 + ir * 8;
    float psumv = 0.f;
    int pcntv = 0;
#pragma unroll
    for (int j = 0; j < 8; ++j) {
        if (j == ir) continue;
        float s = sb[j];
        if (s > mn) { pcntv++; psumv += 1.f - s; }
    }
    float pl = (pcntv > 0) ? psumv / (float)pcntv : 0.f;
    float nl = (ct > 0) ? (2.0f / ALPHA) * log1pf(es) + sm / (float)ct : 0.f;
    rowloss[row] = pl + nl;
    rowtrip[row] = ct >> 1;
}

// ---------------- kernel 3b: deterministic final reduce (single block)
__global__ __launch_bounds__(256) void k_fin2(const float* __restrict__ rowloss,
                                              const unsigned* __restrict__ rowtrip,
                                              float* __restrict__ out) {
    __shared__ float lsum[256];
    __shared__ unsigned long long ltrip[256];
    int t = threadIdx.x;
    float acc = 0.f;
    unsigned long long trip = 0ull;
    for (int it = 0; it < NROWS / 256; ++it) {
        int row = t + it * 256;
        acc += rowloss[row];
        trip += (unsigned long long)rowtrip[row];
    }
    lsum[t] = acc;
    ltrip[t] = trip;
    __syncthreads();
    for (int s = 128; s > 0; s >>= 1) {
        if (t < s) { lsum[t] += lsum[t + s]; ltrip[t] += ltrip[t + s]; }
        __syncthreads();
    }
    if (t == 0) {
        out[0] = lsum[0] / (float)NROWS;
        out[1] = (float)ltrip[0];
        out[2] = 0.f;
    }
}

extern "C" void kernel_launch(void* const* d_in, const int* in_sizes, int n_in,
                              void* d_out, int out_size, void* d_ws, size_t ws_size,
                              hipStream_t stream) {
    const float* emb = (const float*)d_in[0];
    char* ws = (char*)d_ws;
    unsigned short* ehi = (unsigned short*)(ws + OFF_HI);
    unsigned short* elo = (unsigned short*)(ws + OFF_LO);
    float* maxpos = (float*)(ws + OFF_MAXP);
    float* simblk = (float*)(ws + OFF_SBLK);
    float* pmin = (float*)(ws + OFF_PMIN);
    unsigned* pcnt = (unsigned*)(ws + OFF_PCNT);
    float* psum = (float*)(ws + OFF_PSUM);
    float* pexp = (float*)(ws + OFF_PEXP);
    float* rowloss = (float*)(ws + OFF_RLOSS);
    unsigned* rowtrip = (unsigned*)(ws + OFF_RTRIP);
    float* out = (float*)d_out;

    hipLaunchKernelGGL(k_prep, dim3(64 * NROWS / 256), dim3(256), 0, stream,
                       emb, (uint4*)ehi, (uint4*)elo);
    hipLaunchKernelGGL(k_gram, dim3(1024), dim3(64), 0, stream, emb, simblk, maxpos);
    hipLaunchKernelGGL(k_main, dim3(NPAIRS), dim3(256), 0, stream,
                       ehi, elo, maxpos, pmin, pcnt, psum, pexp);
    hipLaunchKernelGGL(k_fin1, dim3(NROWS / 256), dim3(256), 0, stream,
                       pmin, pcnt, psum, pexp, simblk, rowloss, rowtrip);
    hipLaunchKernelGGL(k_fin2, dim3(1), dim3(256), 0, stream, rowloss, rowtrip, out);
}